// Round 7
// baseline (243.771 us; speedup 1.0000x reference)
//
#include <hip/hip_runtime.h>
#include <cstddef>

// Problem constants (from reference)
#define QN 10000
#define DD 64
#define MM 50
#define BB 64
#define TT 512
#define WPAD 52   // padded w row stride in floats (208 B -> 16B-aligned rows)
#define MG 25     // m's per wave in the 2-way m-split scan kernels

// ===========================================================================
// MAIN PATH (C == 32), 3 dispatches:
//   kPreA : per-(b,chunk) block computes w/e/a for its 16 rows (global+LDS)
//           then composes the chunk affine (A,B) from LDS. Fuses kPre+kA.
//   kB    : cross-chunk prefix (unchanged).
//   kCD   : per-(b,chunk) block replays the chunk, read-rows go to LDS,
//           then the same waves run the output MLP. Fuses kC+k3; kills the
//           33MB read2 round-trip.
// Register discipline: waves_per_eu(1,2) pins the budget to <=256 VGPR so
// weight arrays stay in registers (round-6's k3 showed VGPR=72 + fw[128]
// => in-loop reloads; round-4's kD showed (1,2) keeps 148 live).
// ===========================================================================

__global__ __attribute__((amdgpu_waves_per_eu(1, 2))) __launch_bounds__(192)
void kPreA(
    const int* __restrict__ question, const int* __restrict__ response,
    const float* __restrict__ mask,
    const float* __restrict__ k_emb, const float* __restrict__ v_emb,
    const float* __restrict__ Mk,
    const float* __restrict__ e_W, const float* __restrict__ e_b,
    const float* __restrict__ a_W, const float* __restrict__ a_b,
    float* __restrict__ w_buf, float* __restrict__ e_buf,
    float* __restrict__ a_buf, float* __restrict__ AB) {
  __shared__ float w_lds[16][52];
  __shared__ float e_lds[16][64];
  __shared__ float a_lds[16][64];
  const int lane = (int)(threadIdx.x & 63);
  const int wslot = __builtin_amdgcn_readfirstlane((int)(threadIdx.x >> 6)); // 0..2
  const int unit = blockIdx.x;                         // b*32 + c
  const int b = unit >> 5;
  const int c = unit & 31;
  const size_t rowbase = (size_t)b * TT + c * 16;

  if (wslot == 0) {                       // ---- role: w (softmax), 16 rows
    float mk[64];
    const int mrow = lane < MM ? lane : (MM - 1);
#pragma unroll
    for (int i = 0; i < 64; i += 4) {
      const float4 t4 = *(const float4*)(Mk + mrow * 64 + i);
      mk[i] = t4.x; mk[i + 1] = t4.y; mk[i + 2] = t4.z; mk[i + 3] = t4.w;
    }
#pragma unroll
    for (int base = 0; base < 16; base += 4) {
      const int4 q4 = *(const int4*)(question + rowbase + base);
      const float* __restrict__ kr0 = k_emb + (size_t)q4.x * 64;
      const float* __restrict__ kr1 = k_emb + (size_t)q4.y * 64;
      const float* __restrict__ kr2 = k_emb + (size_t)q4.z * 64;
      const float* __restrict__ kr3 = k_emb + (size_t)q4.w * 64;
      float l00=0.f,l01=0.f,l02=0.f,l03=0.f;
      float l10=0.f,l11=0.f,l12=0.f,l13=0.f;
      float l20=0.f,l21=0.f,l22=0.f,l23=0.f;
      float l30=0.f,l31=0.f,l32=0.f,l33=0.f;
#pragma unroll
      for (int i = 0; i < 64; i += 4) {
        const float4 k0 = *(const float4*)(kr0 + i);   // 4 independent chains
        const float4 k1 = *(const float4*)(kr1 + i);
        const float4 k2 = *(const float4*)(kr2 + i);
        const float4 k3 = *(const float4*)(kr3 + i);
        l00 = fmaf(k0.x, mk[i], l00); l01 = fmaf(k0.y, mk[i+1], l01);
        l02 = fmaf(k0.z, mk[i+2], l02); l03 = fmaf(k0.w, mk[i+3], l03);
        l10 = fmaf(k1.x, mk[i], l10); l11 = fmaf(k1.y, mk[i+1], l11);
        l12 = fmaf(k1.z, mk[i+2], l12); l13 = fmaf(k1.w, mk[i+3], l13);
        l20 = fmaf(k2.x, mk[i], l20); l21 = fmaf(k2.y, mk[i+1], l21);
        l22 = fmaf(k2.z, mk[i+2], l22); l23 = fmaf(k2.w, mk[i+3], l23);
        l30 = fmaf(k3.x, mk[i], l30); l31 = fmaf(k3.y, mk[i+1], l31);
        l32 = fmaf(k3.z, mk[i+2], l32); l33 = fmaf(k3.w, mk[i+3], l33);
      }
      float lm[4];
      lm[0] = (l00 + l01) + (l02 + l03);
      lm[1] = (l10 + l11) + (l12 + l13);
      lm[2] = (l20 + l21) + (l22 + l23);
      lm[3] = (l30 + l31) + (l32 + l33);
#pragma unroll
      for (int r = 0; r < 4; ++r) {
        float lv = (lane < MM) ? lm[r] : -3.4e38f;
#pragma unroll
        for (int off = 32; off > 0; off >>= 1) lv = fmaxf(lv, __shfl_xor(lv, off));
        float pe = (lane < MM) ? __expf(lm[r] - lv) : 0.f;
        float ss = pe;
#pragma unroll
        for (int off = 32; off > 0; off >>= 1) ss += __shfl_xor(ss, off);
        if (lane < MM) {
          const float wv = pe / ss;
          w_buf[(rowbase + base + r) * WPAD + lane] = wv;
          w_lds[base + r][lane] = wv;
        }
      }
    }
  } else if (wslot == 1) {                // ---- role: e, 16 rows
    float ew[64];
#pragma unroll
    for (int i = 0; i < 64; ++i) ew[i] = e_W[i * 64 + lane];
    const float eb = e_b[lane];
#pragma unroll
    for (int base = 0; base < 16; base += 4) {
      const int4 q4 = *(const int4*)(question + rowbase + base);
      const int4 r4 = *(const int4*)(response + rowbase + base);
      const float4 m4 = *(const float4*)(mask + rowbase + base);
      const float* __restrict__ v0 = v_emb + ((size_t)q4.x + (size_t)QN * r4.x) * 64;
      const float* __restrict__ v1 = v_emb + ((size_t)q4.y + (size_t)QN * r4.y) * 64;
      const float* __restrict__ v2 = v_emb + ((size_t)q4.z + (size_t)QN * r4.z) * 64;
      const float* __restrict__ v3 = v_emb + ((size_t)q4.w + (size_t)QN * r4.w) * 64;
      float e00 = eb, e01 = 0.f, e10 = eb, e11 = 0.f;
      float e20 = eb, e21 = 0.f, e30 = eb, e31 = 0.f;
#pragma unroll
      for (int i = 0; i < 64; i += 2) {
        const float2 a0 = *(const float2*)(v0 + i);
        const float2 a1 = *(const float2*)(v1 + i);
        const float2 a2 = *(const float2*)(v2 + i);
        const float2 a3 = *(const float2*)(v3 + i);
        e00 = fmaf(a0.x, ew[i], e00); e01 = fmaf(a0.y, ew[i+1], e01);
        e10 = fmaf(a1.x, ew[i], e10); e11 = fmaf(a1.y, ew[i+1], e11);
        e20 = fmaf(a2.x, ew[i], e20); e21 = fmaf(a2.y, ew[i+1], e21);
        e30 = fmaf(a3.x, ew[i], e30); e31 = fmaf(a3.y, ew[i+1], e31);
      }
      const float mf0 = (m4.x == 1.0f) ? 1.0f : 0.0f;
      const float mf1 = (m4.y == 1.0f) ? 1.0f : 0.0f;
      const float mf2 = (m4.z == 1.0f) ? 1.0f : 0.0f;
      const float mf3 = (m4.w == 1.0f) ? 1.0f : 0.0f;
      const float o0 = mf0 / (1.f + __expf(-(e00 + e01)));
      const float o1 = mf1 / (1.f + __expf(-(e10 + e11)));
      const float o2 = mf2 / (1.f + __expf(-(e20 + e21)));
      const float o3 = mf3 / (1.f + __expf(-(e30 + e31)));
      e_buf[(rowbase + base + 0) * 64 + lane] = o0; e_lds[base + 0][lane] = o0;
      e_buf[(rowbase + base + 1) * 64 + lane] = o1; e_lds[base + 1][lane] = o1;
      e_buf[(rowbase + base + 2) * 64 + lane] = o2; e_lds[base + 2][lane] = o2;
      e_buf[(rowbase + base + 3) * 64 + lane] = o3; e_lds[base + 3][lane] = o3;
    }
  } else {                                // ---- role: a, 16 rows
    float aw[64];
#pragma unroll
    for (int i = 0; i < 64; ++i) aw[i] = a_W[i * 64 + lane];
    const float ab = a_b[lane];
#pragma unroll
    for (int base = 0; base < 16; base += 4) {
      const int4 q4 = *(const int4*)(question + rowbase + base);
      const int4 r4 = *(const int4*)(response + rowbase + base);
      const float4 m4 = *(const float4*)(mask + rowbase + base);
      const float* __restrict__ v0 = v_emb + ((size_t)q4.x + (size_t)QN * r4.x) * 64;
      const float* __restrict__ v1 = v_emb + ((size_t)q4.y + (size_t)QN * r4.y) * 64;
      const float* __restrict__ v2 = v_emb + ((size_t)q4.z + (size_t)QN * r4.z) * 64;
      const float* __restrict__ v3 = v_emb + ((size_t)q4.w + (size_t)QN * r4.w) * 64;
      float a00 = ab, a01 = 0.f, a10 = ab, a11 = 0.f;
      float a20 = ab, a21 = 0.f, a30 = ab, a31 = 0.f;
#pragma unroll
      for (int i = 0; i < 64; i += 2) {
        const float2 x0 = *(const float2*)(v0 + i);
        const float2 x1 = *(const float2*)(v1 + i);
        const float2 x2 = *(const float2*)(v2 + i);
        const float2 x3 = *(const float2*)(v3 + i);
        a00 = fmaf(x0.x, aw[i], a00); a01 = fmaf(x0.y, aw[i+1], a01);
        a10 = fmaf(x1.x, aw[i], a10); a11 = fmaf(x1.y, aw[i+1], a11);
        a20 = fmaf(x2.x, aw[i], a20); a21 = fmaf(x2.y, aw[i+1], a21);
        a30 = fmaf(x3.x, aw[i], a30); a31 = fmaf(x3.y, aw[i+1], a31);
      }
      const float mf0 = (m4.x == 1.0f) ? 1.0f : 0.0f;
      const float mf1 = (m4.y == 1.0f) ? 1.0f : 0.0f;
      const float mf2 = (m4.z == 1.0f) ? 1.0f : 0.0f;
      const float mf3 = (m4.w == 1.0f) ? 1.0f : 0.0f;
      const float s0 = a00 + a01, s1 = a10 + a11, s2 = a20 + a21, s3 = a30 + a31;
      const float o0 = mf0 * (1.f - 2.f / (__expf(2.f * s0) + 1.f));
      const float o1 = mf1 * (1.f - 2.f / (__expf(2.f * s1) + 1.f));
      const float o2 = mf2 * (1.f - 2.f / (__expf(2.f * s2) + 1.f));
      const float o3 = mf3 * (1.f - 2.f / (__expf(2.f * s3) + 1.f));
      a_buf[(rowbase + base + 0) * 64 + lane] = o0; a_lds[base + 0][lane] = o0;
      a_buf[(rowbase + base + 1) * 64 + lane] = o1; a_lds[base + 1][lane] = o1;
      a_buf[(rowbase + base + 2) * 64 + lane] = o2; a_lds[base + 2][lane] = o2;
      a_buf[(rowbase + base + 3) * 64 + lane] = o3; a_lds[base + 3][lane] = o3;
    }
  }
  __syncthreads();

  // ---- phase 2: waves 0,1 compose the chunk affine (g = wslot)
  if (wslot < 2) {
    const int g = wslot;
    float Am[MG], Bm[MG];
#pragma unroll
    for (int m = 0; m < MG; ++m) { Am[m] = 1.f; Bm[m] = 0.f; }
#pragma unroll
    for (int j = 0; j < 16; ++j) {
      const float ed = e_lds[j][lane];
      const float ad = a_lds[j][lane];
#pragma unroll
      for (int m = 0; m < MG; ++m) {
        const float wm = w_lds[j][g * MG + m];         // LDS broadcast
        const float al = fmaf(-wm, ed, 1.0f);
        const float be = wm * ad;
        Am[m] *= al;
        Bm[m] = fmaf(Bm[m], al, be);
      }
    }
    float* __restrict__ abp = AB + (size_t)unit * 6400 + (g * MG) * 128 + lane * 2;
#pragma unroll
    for (int m = 0; m < MG; ++m) {
      float2 o; o.x = Am[m]; o.y = Bm[m];
      *(float2*)(abp + m * 128) = o;
    }
  }
}

// ===========================================================================
// kB: sequential over C chunks, parallel over B*M*D = 204,800 elements.
// ===========================================================================
__global__ __launch_bounds__(256) void kB_entry(
    const float* __restrict__ AB, const float* __restrict__ Mv0,
    float* __restrict__ entry, int C) {
  const int NT = gridDim.x * 256;
  for (int idx = blockIdx.x * 256 + (int)threadIdx.x; idx < BB * MM * 64;
       idx += NT) {
    const int b = idx / (MM * 64);
    const int r = idx - b * (MM * 64);                 // m*64 + d
    float s = Mv0[r];
    const float* __restrict__ abp = AB + (size_t)b * C * 6400 + (size_t)r * 2;
    float* __restrict__ ep = entry + (size_t)b * C * 3200 + r;
    if (C == 32) {
      float2 ab[32];
#pragma unroll
      for (int c = 0; c < 32; ++c)
        ab[c] = *(const float2*)(abp + (size_t)c * 6400);
#pragma unroll
      for (int c = 0; c < 32; ++c) {
        ep[(size_t)c * 3200] = s;
        s = fmaf(ab[c].x, s, ab[c].y);
      }
    } else {
      float2 cur = *(const float2*)(abp);
      for (int c = 0; c < C; ++c) {
        ep[(size_t)c * 3200] = s;
        float2 nxt; nxt.x = 1.f; nxt.y = 0.f;
        if (c + 1 < C) nxt = *(const float2*)(abp + (size_t)(c + 1) * 6400);
        s = fmaf(cur.x, s, cur.y);
        cur = nxt;
      }
    }
  }
}

// ===========================================================================
// kCD: fused replay + output MLP, block = (b,chunk), 2 waves.
// Phase 1 (scan): wave g replays its 25-m half from entry; partial read rows
//   -> p_lds[g][j][d] (no global read2).
// Phase 2 (MLP): each wave takes 8 of the 16 rows; read-row via uniform LDS
//   broadcasts (p0+p1), k-row via uniform s_loads, fw[128] in registers.
// ===========================================================================
__global__ __attribute__((amdgpu_waves_per_eu(1, 2))) __launch_bounds__(128)
void kCD(
    const int* __restrict__ question,
    const float* __restrict__ w_buf, const float* __restrict__ e_buf,
    const float* __restrict__ a_buf, const float* __restrict__ entry,
    const float* __restrict__ k_emb,
    const float* __restrict__ f_W, const float* __restrict__ f_b,
    const float* __restrict__ p_W, const float* __restrict__ p_b,
    float* __restrict__ out) {
  __shared__ float p_lds[2][16][64];
  const int lane = (int)(threadIdx.x & 63);
  const int g = __builtin_amdgcn_readfirstlane((int)(threadIdx.x >> 6)); // 0,1
  const int unit = blockIdx.x;                         // b*32 + c
  const int b = unit >> 5;
  const int c = unit & 31;
  const size_t rowbase = (size_t)b * TT + c * 16;
  const size_t eb0 = rowbase * 64 + lane;

  // ---- phase 1: scan (as kC16, partials to LDS)
  {
    float ev[16], av[16];
#pragma unroll
    for (int j = 0; j < 16; ++j) {
      ev[j] = e_buf[eb0 + (size_t)j * 64];
      av[j] = a_buf[eb0 + (size_t)j * 64];
    }
    float s[MG];
    const float* __restrict__ ep =
        entry + (size_t)unit * 3200 + (g * MG) * 64 + lane;
#pragma unroll
    for (int m = 0; m < MG; ++m) s[m] = ep[m * 64];    // 25 independent loads

#pragma unroll
    for (int j = 0; j < 16; ++j) {
      const float* __restrict__ wr = w_buf + (rowbase + j) * WPAD + g * MG;
      float a0 = 0.f, a1 = 0.f;
#pragma unroll
      for (int m = 0; m < MG - 1; m += 2) {
        a0 = fmaf(wr[m], s[m], a0);
        a1 = fmaf(wr[m + 1], s[m + 1], a1);
      }
      a0 = fmaf(wr[MG - 1], s[MG - 1], a0);            // MG=25 is odd
      p_lds[g][j][lane] = a0 + a1;
#pragma unroll
      for (int m = 0; m < MG; ++m)
        s[m] = fmaf(wr[m], fmaf(-s[m], ev[j], av[j]), s[m]);
    }
  }
  __syncthreads();

  // ---- phase 2: output MLP, 8 rows per wave
  float fw[128];
#pragma unroll
  for (int i = 0; i < 128; ++i) fw[i] = f_W[i * 64 + lane];
  const float fb = f_b[lane];
  const float pw = p_W[lane];
  const float pb = p_b[0];

  int j0 = g * 8;
  const int j1 = j0 + 8;
  if (c == 0 && g == 0) j0 = 1;                        // t=0 emits no read
  for (int j = j0; j < j1; ++j) {
    const int t = c * 16 + j;
    const int qn = question[(size_t)b * TT + t];       // wave-uniform
    const float* __restrict__ krow = k_emb + (size_t)qn * 64;
    float f0 = fb, f1 = 0.f, f2 = 0.f, f3 = 0.f;
#pragma unroll
    for (int i = 0; i < 64; i += 4) {
      const float4 x0 = *(const float4*)(&p_lds[0][j][i]); // uniform -> bcast
      const float4 x1 = *(const float4*)(&p_lds[1][j][i]);
      f0 = fmaf(x0.x + x1.x, fw[i], f0);
      f1 = fmaf(x0.y + x1.y, fw[i + 1], f1);
      f2 = fmaf(x0.z + x1.z, fw[i + 2], f2);
      f3 = fmaf(x0.w + x1.w, fw[i + 3], f3);
    }
#pragma unroll
    for (int i = 0; i < 64; i += 4) {
      const float4 kv = *(const float4*)(krow + i);    // uniform -> s_load
      f0 = fmaf(kv.x, fw[64 + i], f0);
      f1 = fmaf(kv.y, fw[64 + i + 1], f1);
      f2 = fmaf(kv.z, fw[64 + i + 2], f2);
      f3 = fmaf(kv.w, fw[64 + i + 3], f3);
    }
    const float fsum = (f0 + f1) + (f2 + f3);
    const float t2 = __expf(2.f * fsum);
    const float fv = 1.f - 2.f / (t2 + 1.f);           // tanh
    float acc = fv * pw;
#pragma unroll
    for (int off = 32; off > 0; off >>= 1) acc += __shfl_xor(acc, off);
    if (lane == 0) out[(size_t)b * (TT - 1) + (t - 1)] = acc + pb;
  }
}

// ===========================================================================
// FALLBACK PATH (only if workspace can't hold C=32): round-5 proven kernels.
// ===========================================================================
__global__ __launch_bounds__(256) void kPre(
    const int* __restrict__ question, const int* __restrict__ response,
    const float* __restrict__ mask,
    const float* __restrict__ k_emb, const float* __restrict__ v_emb,
    const float* __restrict__ Mk,
    const float* __restrict__ e_W, const float* __restrict__ e_b,
    const float* __restrict__ a_W, const float* __restrict__ a_b,
    float* __restrict__ w_buf, float* __restrict__ e_buf,
    float* __restrict__ a_buf) {
  const int lane = (int)(threadIdx.x & 63);
  const int wslot = __builtin_amdgcn_readfirstlane((int)(threadIdx.x >> 6));
  const int gw = blockIdx.x * 4 + wslot;
  const int NW = gridDim.x * 4;
  const int third = NW / 3;
  if (gw >= 3 * third) return;
  const int role = gw / third;
  const int idx = gw - role * third;

  if (role == 0) {
    float mk[64];
    const int mrow = lane < MM ? lane : (MM - 1);
#pragma unroll
    for (int i = 0; i < 64; i += 4) {
      const float4 t4 = *(const float4*)(Mk + mrow * 64 + i);
      mk[i] = t4.x; mk[i + 1] = t4.y; mk[i + 2] = t4.z; mk[i + 3] = t4.w;
    }
    for (int row = idx; row < BB * TT; row += third) {
      const int q = question[row];
      const float* __restrict__ krow = k_emb + (size_t)q * 64;
      float l0 = 0.f, l1 = 0.f, l2 = 0.f, l3 = 0.f;
#pragma unroll
      for (int i = 0; i < 64; i += 4) {
        const float4 kv = *(const float4*)(krow + i);
        l0 = fmaf(kv.x, mk[i], l0);
        l1 = fmaf(kv.y, mk[i + 1], l1);
        l2 = fmaf(kv.z, mk[i + 2], l2);
        l3 = fmaf(kv.w, mk[i + 3], l3);
      }
      const float lm = (l0 + l1) + (l2 + l3);
      float lv = (lane < MM) ? lm : -3.4e38f;
#pragma unroll
      for (int off = 32; off > 0; off >>= 1) lv = fmaxf(lv, __shfl_xor(lv, off));
      float pe = (lane < MM) ? __expf(lm - lv) : 0.f;
      float ss = pe;
#pragma unroll
      for (int off = 32; off > 0; off >>= 1) ss += __shfl_xor(ss, off);
      if (lane < MM) w_buf[(size_t)row * WPAD + lane] = pe / ss;
    }
  } else if (role == 1) {
    float ew[64];
#pragma unroll
    for (int i = 0; i < 64; ++i) ew[i] = e_W[i * 64 + lane];
    const float eb = e_b[lane];
    for (int row = idx; row < BB * TT; row += third) {
      const int q = question[row];
      const int r = response[row];
      const float mf = (mask[row] == 1.0f) ? 1.0f : 0.0f;
      const float* __restrict__ vrow = v_emb + ((size_t)q + (size_t)QN * r) * 64;
      float e0 = eb, e1 = 0.f;
#pragma unroll
      for (int i = 0; i < 64; i += 2) {
        const float2 vv = *(const float2*)(vrow + i);
        e0 = fmaf(vv.x, ew[i], e0);
        e1 = fmaf(vv.y, ew[i + 1], e1);
      }
      e_buf[(size_t)row * 64 + lane] = mf / (1.f + __expf(-(e0 + e1)));
    }
  } else {
    float aw[64];
#pragma unroll
    for (int i = 0; i < 64; ++i) aw[i] = a_W[i * 64 + lane];
    const float ab = a_b[lane];
    for (int row = idx; row < BB * TT; row += third) {
      const int q = question[row];
      const int r = response[row];
      const float mf = (mask[row] == 1.0f) ? 1.0f : 0.0f;
      const float* __restrict__ vrow = v_emb + ((size_t)q + (size_t)QN * r) * 64;
      float a0 = ab, a1 = 0.f;
#pragma unroll
      for (int i = 0; i < 64; i += 2) {
        const float2 vv = *(const float2*)(vrow + i);
        a0 = fmaf(vv.x, aw[i], a0);
        a1 = fmaf(vv.y, aw[i + 1], a1);
      }
      const float sa = a0 + a1;
      a_buf[(size_t)row * 64 + lane] = mf * (1.f - 2.f / (__expf(2.f * sa) + 1.f));
    }
  }
}

__global__ __launch_bounds__(256) void kA_chunk(
    const float* __restrict__ w_buf, const float* __restrict__ e_buf,
    const float* __restrict__ a_buf, float* __restrict__ AB, int logC, int L) {
  const int lane = (int)(threadIdx.x & 63);
  const int wslot = __builtin_amdgcn_readfirstlane((int)(threadIdx.x >> 6));
  const int NW = gridDim.x * 4;
  const int C = 1 << logC;
  for (int u2 = blockIdx.x * 4 + wslot; u2 < BB * C * 2; u2 += NW) {
    const int g = u2 & 1;
    const int unit = u2 >> 1;
    const int b = unit >> logC;
    const int c = unit & (C - 1);
    float Am[MG], Bm[MG];
#pragma unroll
    for (int m = 0; m < MG; ++m) { Am[m] = 1.f; Bm[m] = 0.f; }
    const size_t rowbase = (size_t)b * TT + c * L;
#pragma unroll 2
    for (int j = 0; j < L; ++j) {
      const size_t row = rowbase + j;
      const float ed = e_buf[row * 64 + lane];
      const float ad = a_buf[row * 64 + lane];
      const float* __restrict__ wr = w_buf + row * WPAD + g * MG;
#pragma unroll
      for (int m = 0; m < MG; ++m) {
        const float wm = wr[m];
        const float al = fmaf(-wm, ed, 1.0f);
        const float be = wm * ad;
        Am[m] *= al;
        Bm[m] = fmaf(Bm[m], al, be);
      }
    }
    float* __restrict__ abp = AB + (size_t)unit * 6400 + (g * MG) * 128 + lane * 2;
#pragma unroll
    for (int m = 0; m < MG; ++m) {
      float2 o; o.x = Am[m]; o.y = Bm[m];
      *(float2*)(abp + m * 128) = o;
    }
  }
}

__global__ __launch_bounds__(256) void kC_read(
    const float* __restrict__ w_buf, const float* __restrict__ e_buf,
    const float* __restrict__ a_buf, const float* __restrict__ entry,
    const float* __restrict__ Mv0, float* __restrict__ read2,
    int logC, int L, int use_mv0) {
  const int lane = (int)(threadIdx.x & 63);
  const int wslot = __builtin_amdgcn_readfirstlane((int)(threadIdx.x >> 6));
  const int NW = gridDim.x * 4;
  const int C = 1 << logC;
  const size_t RN = (size_t)BB * (TT - 1) * 64;
  for (int u2 = blockIdx.x * 4 + wslot; u2 < BB * C * 2; u2 += NW) {
    const int g = u2 & 1;
    const int unit = u2 >> 1;
    const int b = unit >> logC;
    const int c = unit & (C - 1);
    float s[MG];
    if (use_mv0) {
#pragma unroll
      for (int m = 0; m < MG; ++m) s[m] = Mv0[(g * MG + m) * 64 + lane];
    } else {
      const float* __restrict__ ep =
          entry + (size_t)unit * 3200 + (g * MG) * 64 + lane;
#pragma unroll
      for (int m = 0; m < MG; ++m) s[m] = ep[m * 64];
    }
    const int t0 = c * L;
    float* __restrict__ rb = read2 + (size_t)g * RN;
    for (int j = 0; j < L; ++j) {
      const int t = t0 + j;
      const size_t row = (size_t)b * TT + t;
      const float ed = e_buf[row * 64 + lane];
      const float ad = a_buf[row * 64 + lane];
      const float* __restrict__ wr = w_buf + row * WPAD + g * MG;
      if (t >= 1) {
        float a0 = 0.f, a1 = 0.f;
#pragma unroll
        for (int m = 0; m < MG - 1; m += 2) {
          a0 = fmaf(wr[m], s[m], a0);
          a1 = fmaf(wr[m + 1], s[m + 1], a1);
        }
        a0 = fmaf(wr[MG - 1], s[MG - 1], a0);
        rb[((size_t)b * (TT - 1) + (t - 1)) * 64 + lane] = a0 + a1;
      }
#pragma unroll
      for (int m = 0; m < MG; ++m)
        s[m] = fmaf(wr[m], fmaf(-s[m], ed, ad), s[m]);
    }
  }
}

__global__ __attribute__((amdgpu_waves_per_eu(1, 2))) __launch_bounds__(256)
void k3_out(
    const int* __restrict__ question, const float* __restrict__ k_emb,
    const float* __restrict__ read2,
    const float* __restrict__ f_W, const float* __restrict__ f_b,
    const float* __restrict__ p_W, const float* __restrict__ p_b,
    float* __restrict__ out) {
  const int lane = (int)(threadIdx.x & 63);
  const int wslot = __builtin_amdgcn_readfirstlane((int)(threadIdx.x >> 6));
  const int NW = gridDim.x * 4;
  const size_t RN = (size_t)BB * (TT - 1) * 64;

  float fw[128];
#pragma unroll
  for (int i = 0; i < 128; ++i) fw[i] = f_W[i * 64 + lane];
  const float fb = f_b[lane];
  const float pw = p_W[lane];
  const float pb = p_b[0];

  for (int row = blockIdx.x * 4 + wslot; row < BB * (TT - 1); row += NW) {
    const int b = row / (TT - 1);
    const int tp = row - b * (TT - 1);
    const float* __restrict__ r0 = read2 + (size_t)row * 64;
    const float* __restrict__ r1 = r0 + RN;
    const int qn = question[b * TT + tp + 1];
    const float* __restrict__ krow = k_emb + (size_t)qn * 64;

    float f0 = fb, f1 = 0.f, f2 = 0.f, f3 = 0.f;
#pragma unroll
    for (int i = 0; i < 64; i += 4) {
      const float4 x0 = *(const float4*)(r0 + i);
      const float4 x1 = *(const float4*)(r1 + i);
      f0 = fmaf(x0.x + x1.x, fw[i], f0);
      f1 = fmaf(x0.y + x1.y, fw[i + 1], f1);
      f2 = fmaf(x0.z + x1.z, fw[i + 2], f2);
      f3 = fmaf(x0.w + x1.w, fw[i + 3], f3);
    }
#pragma unroll
    for (int i = 0; i < 64; i += 4) {
      const float4 kv = *(const float4*)(krow + i);
      f0 = fmaf(kv.x, fw[64 + i], f0);
      f1 = fmaf(kv.y, fw[64 + i + 1], f1);
      f2 = fmaf(kv.z, fw[64 + i + 2], f2);
      f3 = fmaf(kv.w, fw[64 + i + 3], f3);
    }
    const float f = (f0 + f1) + (f2 + f3);
    const float t2 = __expf(2.f * f);
    const float fv = 1.f - 2.f / (t2 + 1.f);
    float acc = fv * pw;
#pragma unroll
    for (int off = 32; off > 0; off >>= 1) acc += __shfl_xor(acc, off);
    if (lane == 0) out[row] = acc + pb;
  }
}

// ---------------------------------------------------------------------------
extern "C" void kernel_launch(void* const* d_in, const int* in_sizes, int n_in,
                              void* d_out, int out_size, void* d_ws, size_t ws_size,
                              hipStream_t stream) {
  const int*   question = (const int*)d_in[0];
  const int*   response = (const int*)d_in[1];
  const float* mask     = (const float*)d_in[2];
  const float* k_emb    = (const float*)d_in[3];
  const float* v_emb    = (const float*)d_in[4];
  const float* Mk       = (const float*)d_in[5];
  const float* Mv0      = (const float*)d_in[6];
  const float* e_W      = (const float*)d_in[7];
  const float* e_b      = (const float*)d_in[8];
  const float* a_W      = (const float*)d_in[9];
  const float* a_b      = (const float*)d_in[10];
  const float* f_W      = (const float*)d_in[11];
  const float* f_b      = (const float*)d_in[12];
  const float* p_W      = (const float*)d_in[13];
  const float* p_b      = (const float*)d_in[14];
  float* out = (float*)d_out;

  const size_t wN = (size_t)BB * TT * WPAD;        // 1,703,936
  const size_t eN = (size_t)BB * TT * 64;          // 2,097,152
  float* ws = (float*)d_ws;
  float* w_buf = ws;
  float* e_buf = w_buf + wN;
  float* a_buf = e_buf + eN;

  // main path needs: w,e,a + AB(6400*B*32) + entry(3200*B*32) = ~102 MB
  const size_t mainNeed = (wN + 2 * eN + 9600ull * BB * 32) * sizeof(float);
  if (mainNeed <= ws_size) {
    float* AB_arr = a_buf + eN;
    float* entry  = AB_arr + 6400ull * BB * 32;
    hipLaunchKernelGGL(kPreA, dim3(BB * 32), dim3(192), 0, stream,
                       question, response, mask, k_emb, v_emb, Mk,
                       e_W, e_b, a_W, a_b, w_buf, e_buf, a_buf, AB_arr);
    hipLaunchKernelGGL(kB_entry, dim3((BB * MM * 64 + 255) / 256), dim3(256),
                       0, stream, AB_arr, Mv0, entry, 32);
    hipLaunchKernelGGL(kCD, dim3(BB * 32), dim3(128), 0, stream,
                       question, w_buf, e_buf, a_buf, entry, k_emb,
                       f_W, f_b, p_W, p_b, out);
    return;
  }

  // fallback: round-5 5-dispatch pipeline with read2
  const size_t r2N = 2ull * BB * (TT - 1) * 64;
  float* read2  = a_buf + eN;
  float* AB_arr = read2 + r2N;
  const size_t baseN = wN + 2 * eN + r2N;
  int C = 32, logC = 5;
  while (C >= 2) {
    const size_t need = (baseN + 9600ull * BB * C) * sizeof(float);
    if (need <= ws_size) break;
    C >>= 1; logC -= 1;
  }
  int useChunks = (C >= 2);
  if (!useChunks) { C = 1; logC = 0; }
  const int L = TT / C;
  float* entry = AB_arr + 6400ull * BB * C;

  hipLaunchKernelGGL(kPre, dim3(2048), dim3(256), 0, stream,
                     question, response, mask, k_emb, v_emb, Mk,
                     e_W, e_b, a_W, a_b, w_buf, e_buf, a_buf);
  if (useChunks) {
    const int ublocksA = (BB * C * 2 + 3) / 4;
    hipLaunchKernelGGL(kA_chunk, dim3(ublocksA), dim3(256), 0, stream,
                       w_buf, e_buf, a_buf, AB_arr, logC, L);
    hipLaunchKernelGGL(kB_entry, dim3((BB * MM * 64 + 255) / 256), dim3(256),
                       0, stream, AB_arr, Mv0, entry, C);
  }
  const int ublocksC = (BB * C * 2 + 3) / 4;
  hipLaunchKernelGGL(kC_read, dim3(ublocksC), dim3(256), 0, stream,
                     w_buf, e_buf, a_buf, entry, Mv0, read2,
                     logC, L, useChunks ? 0 : 1);
  hipLaunchKernelGGL(k3_out, dim3(1024), dim3(256), 0, stream,
                     question, k_emb, read2, f_W, f_b, p_W, p_b, out);
}

// Round 8
// 234.244 us; speedup vs baseline: 1.0407x; 1.0407x over previous
//
#include <hip/hip_runtime.h>
#include <cstddef>

// Problem constants (from reference)
#define QN 10000
#define DD 64
#define MM 50
#define BB 64
#define TT 512
#define WPAD 52   // padded w row stride in floats (208 B -> 16B-aligned rows)
#define MG 25     // m's per wave in the 2-way m-split scan kernels

// ===========================================================================
// kPre: one dispatch for all per-timestep precompute, 4 ROWS PER WAVE batch
// so four independent embedding-gather chains are in flight.
// amdgpu_waves_per_eu(1,2): pin register budget so mk/ew/aw[64] + the 16
// batch accumulators stay in VGPRs (default allocator squeezes to ~64-72
// regs and demotes them -- R6 evidence: k3 VGPR=72 with fw[128]).
// ===========================================================================
__global__ __attribute__((amdgpu_waves_per_eu(1, 2))) __launch_bounds__(256)
void kPre(
    const int* __restrict__ question, const int* __restrict__ response,
    const float* __restrict__ mask,
    const float* __restrict__ k_emb, const float* __restrict__ v_emb,
    const float* __restrict__ Mk,
    const float* __restrict__ e_W, const float* __restrict__ e_b,
    const float* __restrict__ a_W, const float* __restrict__ a_b,
    float* __restrict__ w_buf, float* __restrict__ e_buf,
    float* __restrict__ a_buf) {
  const int lane = (int)(threadIdx.x & 63);
  const int wslot = __builtin_amdgcn_readfirstlane((int)(threadIdx.x >> 6));
  const int gw = blockIdx.x * 4 + wslot;
  const int NW = gridDim.x * 4;
  const int third = NW / 3;
  if (gw >= 3 * third) return;
  const int role = gw / third;
  const int idx = gw - role * third;
  const int stride4 = third * 4;

  if (role == 0) {                        // ---- role: w (softmax), 4 rows/iter
    float mk[64];
    const int mrow = lane < MM ? lane : (MM - 1);
#pragma unroll
    for (int i = 0; i < 64; i += 4) {
      const float4 t4 = *(const float4*)(Mk + mrow * 64 + i);
      mk[i] = t4.x; mk[i + 1] = t4.y; mk[i + 2] = t4.z; mk[i + 3] = t4.w;
    }
    for (int base = idx * 4; base < BB * TT; base += stride4) {
      const int4 q4 = *(const int4*)(question + base);   // 4 indices, 1 load
      const float* __restrict__ kr0 = k_emb + (size_t)q4.x * 64;
      const float* __restrict__ kr1 = k_emb + (size_t)q4.y * 64;
      const float* __restrict__ kr2 = k_emb + (size_t)q4.z * 64;
      const float* __restrict__ kr3 = k_emb + (size_t)q4.w * 64;
      float l00=0.f,l01=0.f,l02=0.f,l03=0.f;   // row 0, 4-way split
      float l10=0.f,l11=0.f,l12=0.f,l13=0.f;   // row 1
      float l20=0.f,l21=0.f,l22=0.f,l23=0.f;   // row 2
      float l30=0.f,l31=0.f,l32=0.f,l33=0.f;   // row 3
#pragma unroll
      for (int i = 0; i < 64; i += 4) {
        const float4 k0 = *(const float4*)(kr0 + i);     // 4 independent
        const float4 k1 = *(const float4*)(kr1 + i);     // s_load chains
        const float4 k2 = *(const float4*)(kr2 + i);
        const float4 k3 = *(const float4*)(kr3 + i);
        l00 = fmaf(k0.x, mk[i], l00); l01 = fmaf(k0.y, mk[i+1], l01);
        l02 = fmaf(k0.z, mk[i+2], l02); l03 = fmaf(k0.w, mk[i+3], l03);
        l10 = fmaf(k1.x, mk[i], l10); l11 = fmaf(k1.y, mk[i+1], l11);
        l12 = fmaf(k1.z, mk[i+2], l12); l13 = fmaf(k1.w, mk[i+3], l13);
        l20 = fmaf(k2.x, mk[i], l20); l21 = fmaf(k2.y, mk[i+1], l21);
        l22 = fmaf(k2.z, mk[i+2], l22); l23 = fmaf(k2.w, mk[i+3], l23);
        l30 = fmaf(k3.x, mk[i], l30); l31 = fmaf(k3.y, mk[i+1], l31);
        l32 = fmaf(k3.z, mk[i+2], l32); l33 = fmaf(k3.w, mk[i+3], l33);
      }
      float lm[4];
      lm[0] = (l00 + l01) + (l02 + l03);
      lm[1] = (l10 + l11) + (l12 + l13);
      lm[2] = (l20 + l21) + (l22 + l23);
      lm[3] = (l30 + l31) + (l32 + l33);
#pragma unroll
      for (int r = 0; r < 4; ++r) {
        float lv = (lane < MM) ? lm[r] : -3.4e38f;
#pragma unroll
        for (int off = 32; off > 0; off >>= 1) lv = fmaxf(lv, __shfl_xor(lv, off));
        float pe = (lane < MM) ? __expf(lm[r] - lv) : 0.f;
        float ss = pe;
#pragma unroll
        for (int off = 32; off > 0; off >>= 1) ss += __shfl_xor(ss, off);
        if (lane < MM) w_buf[(size_t)(base + r) * WPAD + lane] = pe / ss;
      }
    }
  } else if (role == 1) {                 // ---- role: e, 4 rows/iter
    float ew[64];
#pragma unroll
    for (int i = 0; i < 64; ++i) ew[i] = e_W[i * 64 + lane];
    const float eb = e_b[lane];
    for (int base = idx * 4; base < BB * TT; base += stride4) {
      const int4 q4 = *(const int4*)(question + base);
      const int4 r4 = *(const int4*)(response + base);
      const float4 m4 = *(const float4*)(mask + base);
      const float* __restrict__ v0 = v_emb + ((size_t)q4.x + (size_t)QN * r4.x) * 64;
      const float* __restrict__ v1 = v_emb + ((size_t)q4.y + (size_t)QN * r4.y) * 64;
      const float* __restrict__ v2 = v_emb + ((size_t)q4.z + (size_t)QN * r4.z) * 64;
      const float* __restrict__ v3 = v_emb + ((size_t)q4.w + (size_t)QN * r4.w) * 64;
      float e00 = eb, e01 = 0.f, e10 = eb, e11 = 0.f;
      float e20 = eb, e21 = 0.f, e30 = eb, e31 = 0.f;
#pragma unroll
      for (int i = 0; i < 64; i += 2) {
        const float2 a0 = *(const float2*)(v0 + i);      // 4 independent
        const float2 a1 = *(const float2*)(v1 + i);      // s_load chains
        const float2 a2 = *(const float2*)(v2 + i);
        const float2 a3 = *(const float2*)(v3 + i);
        e00 = fmaf(a0.x, ew[i], e00); e01 = fmaf(a0.y, ew[i+1], e01);
        e10 = fmaf(a1.x, ew[i], e10); e11 = fmaf(a1.y, ew[i+1], e11);
        e20 = fmaf(a2.x, ew[i], e20); e21 = fmaf(a2.y, ew[i+1], e21);
        e30 = fmaf(a3.x, ew[i], e30); e31 = fmaf(a3.y, ew[i+1], e31);
      }
      const float mf0 = (m4.x == 1.0f) ? 1.0f : 0.0f;
      const float mf1 = (m4.y == 1.0f) ? 1.0f : 0.0f;
      const float mf2 = (m4.z == 1.0f) ? 1.0f : 0.0f;
      const float mf3 = (m4.w == 1.0f) ? 1.0f : 0.0f;
      e_buf[(size_t)(base + 0) * 64 + lane] = mf0 / (1.f + __expf(-(e00 + e01)));
      e_buf[(size_t)(base + 1) * 64 + lane] = mf1 / (1.f + __expf(-(e10 + e11)));
      e_buf[(size_t)(base + 2) * 64 + lane] = mf2 / (1.f + __expf(-(e20 + e21)));
      e_buf[(size_t)(base + 3) * 64 + lane] = mf3 / (1.f + __expf(-(e30 + e31)));
    }
  } else {                                // ---- role: a, 4 rows/iter
    float aw[64];
#pragma unroll
    for (int i = 0; i < 64; ++i) aw[i] = a_W[i * 64 + lane];
    const float ab = a_b[lane];
    for (int base = idx * 4; base < BB * TT; base += stride4) {
      const int4 q4 = *(const int4*)(question + base);
      const int4 r4 = *(const int4*)(response + base);
      const float4 m4 = *(const float4*)(mask + base);
      const float* __restrict__ v0 = v_emb + ((size_t)q4.x + (size_t)QN * r4.x) * 64;
      const float* __restrict__ v1 = v_emb + ((size_t)q4.y + (size_t)QN * r4.y) * 64;
      const float* __restrict__ v2 = v_emb + ((size_t)q4.z + (size_t)QN * r4.z) * 64;
      const float* __restrict__ v3 = v_emb + ((size_t)q4.w + (size_t)QN * r4.w) * 64;
      float a00 = ab, a01 = 0.f, a10 = ab, a11 = 0.f;
      float a20 = ab, a21 = 0.f, a30 = ab, a31 = 0.f;
#pragma unroll
      for (int i = 0; i < 64; i += 2) {
        const float2 x0 = *(const float2*)(v0 + i);
        const float2 x1 = *(const float2*)(v1 + i);
        const float2 x2 = *(const float2*)(v2 + i);
        const float2 x3 = *(const float2*)(v3 + i);
        a00 = fmaf(x0.x, aw[i], a00); a01 = fmaf(x0.y, aw[i+1], a01);
        a10 = fmaf(x1.x, aw[i], a10); a11 = fmaf(x1.y, aw[i+1], a11);
        a20 = fmaf(x2.x, aw[i], a20); a21 = fmaf(x2.y, aw[i+1], a21);
        a30 = fmaf(x3.x, aw[i], a30); a31 = fmaf(x3.y, aw[i+1], a31);
      }
      const float mf0 = (m4.x == 1.0f) ? 1.0f : 0.0f;
      const float mf1 = (m4.y == 1.0f) ? 1.0f : 0.0f;
      const float mf2 = (m4.z == 1.0f) ? 1.0f : 0.0f;
      const float mf3 = (m4.w == 1.0f) ? 1.0f : 0.0f;
      const float s0 = a00 + a01, s1 = a10 + a11, s2 = a20 + a21, s3 = a30 + a31;
      a_buf[(size_t)(base + 0) * 64 + lane] = mf0 * (1.f - 2.f / (__expf(2.f * s0) + 1.f));
      a_buf[(size_t)(base + 1) * 64 + lane] = mf1 * (1.f - 2.f / (__expf(2.f * s1) + 1.f));
      a_buf[(size_t)(base + 2) * 64 + lane] = mf2 * (1.f - 2.f / (__expf(2.f * s2) + 1.f));
      a_buf[(size_t)(base + 3) * 64 + lane] = mf3 * (1.f - 2.f / (__expf(2.f * s3) + 1.f));
    }
  }
}

// ===========================================================================
// kA16: C=32 specialized compose (L=16, fully unrolled), prefetch-all ev/av.
// ===========================================================================
__global__ __launch_bounds__(256) void kA16(
    const float* __restrict__ w_buf, const float* __restrict__ e_buf,
    const float* __restrict__ a_buf, float* __restrict__ AB) {
  const int lane = (int)(threadIdx.x & 63);
  const int wslot = __builtin_amdgcn_readfirstlane((int)(threadIdx.x >> 6));
  const int u2 = blockIdx.x * 4 + wslot;
  if (u2 >= BB * 32 * 2) return;
  const int g = u2 & 1;
  const int unit = u2 >> 1;                            // b*32 + c
  const int b = unit >> 5;
  const int c = unit & 31;
  const size_t rowbase = (size_t)b * TT + c * 16;
  const size_t eb0 = rowbase * 64 + lane;

  float ev[16], av[16];
#pragma unroll
  for (int j = 0; j < 16; ++j) {
    ev[j] = e_buf[eb0 + (size_t)j * 64];
    av[j] = a_buf[eb0 + (size_t)j * 64];
  }

  float Am[MG], Bm[MG];
#pragma unroll
  for (int m = 0; m < MG; ++m) { Am[m] = 1.f; Bm[m] = 0.f; }

#pragma unroll
  for (int j = 0; j < 16; ++j) {
    const float* __restrict__ wr = w_buf + (rowbase + j) * WPAD + g * MG;
#pragma unroll
    for (int m = 0; m < MG; ++m) {
      const float wm = wr[m];
      const float al = fmaf(-wm, ev[j], 1.0f);
      const float be = wm * av[j];
      Am[m] *= al;
      Bm[m] = fmaf(Bm[m], al, be);
    }
  }
  float* __restrict__ abp = AB + (size_t)unit * 6400 + (g * MG) * 128 + lane * 2;
#pragma unroll
  for (int m = 0; m < MG; ++m) {
    float2 o; o.x = Am[m]; o.y = Bm[m];
    *(float2*)(abp + m * 128) = o;
  }
}

// ===========================================================================
// kB: sequential over C chunks, parallel over B*M*D = 204,800 elements.
// ===========================================================================
__global__ __launch_bounds__(256) void kB_entry(
    const float* __restrict__ AB, const float* __restrict__ Mv0,
    float* __restrict__ entry, int C) {
  const int NT = gridDim.x * 256;
  for (int idx = blockIdx.x * 256 + (int)threadIdx.x; idx < BB * MM * 64;
       idx += NT) {
    const int b = idx / (MM * 64);
    const int r = idx - b * (MM * 64);                 // m*64 + d
    float s = Mv0[r];
    const float* __restrict__ abp = AB + (size_t)b * C * 6400 + (size_t)r * 2;
    float* __restrict__ ep = entry + (size_t)b * C * 3200 + r;
    if (C == 32) {
      float2 ab[32];
#pragma unroll
      for (int c = 0; c < 32; ++c)
        ab[c] = *(const float2*)(abp + (size_t)c * 6400);
#pragma unroll
      for (int c = 0; c < 32; ++c) {
        ep[(size_t)c * 3200] = s;
        s = fmaf(ab[c].x, s, ab[c].y);
      }
    } else {
      float2 cur = *(const float2*)(abp);
      for (int c = 0; c < C; ++c) {
        ep[(size_t)c * 3200] = s;
        float2 nxt; nxt.x = 1.f; nxt.y = 0.f;
        if (c + 1 < C) nxt = *(const float2*)(abp + (size_t)(c + 1) * 6400);
        s = fmaf(cur.x, s, cur.y);
        cur = nxt;
      }
    }
  }
}

// ===========================================================================
// kC16: C=32 specialized replay (L=16, fully unrolled), prefetch-all ev/av.
// ===========================================================================
__global__ __launch_bounds__(256) void kC16(
    const float* __restrict__ w_buf, const float* __restrict__ e_buf,
    const float* __restrict__ a_buf, const float* __restrict__ entry,
    float* __restrict__ read2) {
  const int lane = (int)(threadIdx.x & 63);
  const int wslot = __builtin_amdgcn_readfirstlane((int)(threadIdx.x >> 6));
  const int u2 = blockIdx.x * 4 + wslot;
  if (u2 >= BB * 32 * 2) return;
  const int g = u2 & 1;
  const int unit = u2 >> 1;                            // b*32 + c
  const int b = unit >> 5;
  const int c = unit & 31;
  const size_t RN = (size_t)BB * (TT - 1) * 64;
  const size_t rowbase = (size_t)b * TT + c * 16;
  const size_t eb0 = rowbase * 64 + lane;

  float ev[16], av[16];
#pragma unroll
  for (int j = 0; j < 16; ++j) {
    ev[j] = e_buf[eb0 + (size_t)j * 64];
    av[j] = a_buf[eb0 + (size_t)j * 64];
  }

  float s[MG];
  {
    const float* __restrict__ ep =
        entry + (size_t)unit * 3200 + (g * MG) * 64 + lane;
#pragma unroll
    for (int m = 0; m < MG; ++m) s[m] = ep[m * 64];    // 25 independent loads
  }

  const int t0 = c * 16;
  float* __restrict__ rb = read2 + (size_t)g * RN;
#pragma unroll
  for (int j = 0; j < 16; ++j) {
    const int t = t0 + j;
    const float* __restrict__ wr = w_buf + (rowbase + j) * WPAD + g * MG;
    if (t >= 1) {                                      // false only c==0,j==0
      float a0 = 0.f, a1 = 0.f;
#pragma unroll
      for (int m = 0; m < MG - 1; m += 2) {
        a0 = fmaf(wr[m], s[m], a0);
        a1 = fmaf(wr[m + 1], s[m + 1], a1);
      }
      a0 = fmaf(wr[MG - 1], s[MG - 1], a0);            // MG=25 is odd
      rb[((size_t)b * (TT - 1) + (t - 1)) * 64 + lane] = a0 + a1;
    }
#pragma unroll
    for (int m = 0; m < MG; ++m)
      s[m] = fmaf(wr[m], fmaf(-s[m], ev[j], av[j]), s[m]);
  }
}

// ===========================================================================
// Generic fallback scan kernels (used only if C != 32).
// ===========================================================================
__global__ __launch_bounds__(256) void kA_chunk(
    const float* __restrict__ w_buf, const float* __restrict__ e_buf,
    const float* __restrict__ a_buf, float* __restrict__ AB, int logC, int L) {
  const int lane = (int)(threadIdx.x & 63);
  const int wslot = __builtin_amdgcn_readfirstlane((int)(threadIdx.x >> 6));
  const int NW = gridDim.x * 4;
  const int C = 1 << logC;
  for (int u2 = blockIdx.x * 4 + wslot; u2 < BB * C * 2; u2 += NW) {
    const int g = u2 & 1;
    const int unit = u2 >> 1;
    const int b = unit >> logC;
    const int c = unit & (C - 1);
    float Am[MG], Bm[MG];
#pragma unroll
    for (int m = 0; m < MG; ++m) { Am[m] = 1.f; Bm[m] = 0.f; }
    const size_t rowbase = (size_t)b * TT + c * L;
#pragma unroll 2
    for (int j = 0; j < L; ++j) {
      const size_t row = rowbase + j;
      const float ed = e_buf[row * 64 + lane];
      const float ad = a_buf[row * 64 + lane];
      const float* __restrict__ wr = w_buf + row * WPAD + g * MG;
#pragma unroll
      for (int m = 0; m < MG; ++m) {
        const float wm = wr[m];
        const float al = fmaf(-wm, ed, 1.0f);
        const float be = wm * ad;
        Am[m] *= al;
        Bm[m] = fmaf(Bm[m], al, be);
      }
    }
    float* __restrict__ abp = AB + (size_t)unit * 6400 + (g * MG) * 128 + lane * 2;
#pragma unroll
    for (int m = 0; m < MG; ++m) {
      float2 o; o.x = Am[m]; o.y = Bm[m];
      *(float2*)(abp + m * 128) = o;
    }
  }
}

__global__ __launch_bounds__(256) void kC_read(
    const float* __restrict__ w_buf, const float* __restrict__ e_buf,
    const float* __restrict__ a_buf, const float* __restrict__ entry,
    const float* __restrict__ Mv0, float* __restrict__ read2,
    int logC, int L, int use_mv0) {
  const int lane = (int)(threadIdx.x & 63);
  const int wslot = __builtin_amdgcn_readfirstlane((int)(threadIdx.x >> 6));
  const int NW = gridDim.x * 4;
  const int C = 1 << logC;
  const size_t RN = (size_t)BB * (TT - 1) * 64;
  for (int u2 = blockIdx.x * 4 + wslot; u2 < BB * C * 2; u2 += NW) {
    const int g = u2 & 1;
    const int unit = u2 >> 1;
    const int b = unit >> logC;
    const int c = unit & (C - 1);
    float s[MG];
    if (use_mv0) {
#pragma unroll
      for (int m = 0; m < MG; ++m) s[m] = Mv0[(g * MG + m) * 64 + lane];
    } else {
      const float* __restrict__ ep =
          entry + (size_t)unit * 3200 + (g * MG) * 64 + lane;
#pragma unroll
      for (int m = 0; m < MG; ++m) s[m] = ep[m * 64];
    }
    const int t0 = c * L;
    float* __restrict__ rb = read2 + (size_t)g * RN;
    for (int j = 0; j < L; ++j) {
      const int t = t0 + j;
      const size_t row = (size_t)b * TT + t;
      const float ed = e_buf[row * 64 + lane];
      const float ad = a_buf[row * 64 + lane];
      const float* __restrict__ wr = w_buf + row * WPAD + g * MG;
      if (t >= 1) {
        float a0 = 0.f, a1 = 0.f;
#pragma unroll
        for (int m = 0; m < MG - 1; m += 2) {
          a0 = fmaf(wr[m], s[m], a0);
          a1 = fmaf(wr[m + 1], s[m + 1], a1);
        }
        a0 = fmaf(wr[MG - 1], s[MG - 1], a0);
        rb[((size_t)b * (TT - 1) + (t - 1)) * 64 + lane] = a0 + a1;
      }
#pragma unroll
      for (int m = 0; m < MG; ++m)
        s[m] = fmaf(wr[m], fmaf(-s[m], ed, ad), s[m]);
    }
  }
}

// ===========================================================================
// k3: f = tanh([read | k_{t+1}] @ f_W + f_b); p = f @ p_W + p_b.
// amdgpu_waves_per_eu(1,2): R6 measured VGPR=72 here -- fw[128] was demoted
// and re-walked every row (46.7us, VALU 28%, HBM 6.6%). Pin the budget so
// fw stays resident (R4 evidence: (1,2) kept 148 VGPRs live).
// ===========================================================================
__global__ __attribute__((amdgpu_waves_per_eu(1, 2))) __launch_bounds__(256)
void k3_out(
    const int* __restrict__ question, const float* __restrict__ k_emb,
    const float* __restrict__ read2,
    const float* __restrict__ f_W, const float* __restrict__ f_b,
    const float* __restrict__ p_W, const float* __restrict__ p_b,
    float* __restrict__ out) {
  const int lane = (int)(threadIdx.x & 63);
  const int wslot = __builtin_amdgcn_readfirstlane((int)(threadIdx.x >> 6));
  const int NW = gridDim.x * 4;
  const size_t RN = (size_t)BB * (TT - 1) * 64;

  float fw[128];
#pragma unroll
  for (int i = 0; i < 128; ++i) fw[i] = f_W[i * 64 + lane];
  const float fb = f_b[lane];
  const float pw = p_W[lane];
  const float pb = p_b[0];

  for (int row = blockIdx.x * 4 + wslot; row < BB * (TT - 1); row += NW) {
    const int b = row / (TT - 1);
    const int tp = row - b * (TT - 1);
    const float* __restrict__ r0 = read2 + (size_t)row * 64;
    const float* __restrict__ r1 = r0 + RN;
    const int qn = question[b * TT + tp + 1];          // wave-uniform
    const float* __restrict__ krow = k_emb + (size_t)qn * 64;

    float f0 = fb, f1 = 0.f, f2 = 0.f, f3 = 0.f;
#pragma unroll
    for (int i = 0; i < 64; i += 4) {
      const float4 x0 = *(const float4*)(r0 + i);
      const float4 x1 = *(const float4*)(r1 + i);
      f0 = fmaf(x0.x + x1.x, fw[i], f0);
      f1 = fmaf(x0.y + x1.y, fw[i + 1], f1);
      f2 = fmaf(x0.z + x1.z, fw[i + 2], f2);
      f3 = fmaf(x0.w + x1.w, fw[i + 3], f3);
    }
#pragma unroll
    for (int i = 0; i < 64; i += 4) {
      const float4 kv = *(const float4*)(krow + i);    // uniform -> s_load
      f0 = fmaf(kv.x, fw[64 + i], f0);
      f1 = fmaf(kv.y, fw[64 + i + 1], f1);
      f2 = fmaf(kv.z, fw[64 + i + 2], f2);
      f3 = fmaf(kv.w, fw[64 + i + 3], f3);
    }
    const float f = (f0 + f1) + (f2 + f3);
    const float t2 = __expf(2.f * f);
    const float fv = 1.f - 2.f / (t2 + 1.f);           // tanh
    float acc = fv * pw;
#pragma unroll
    for (int off = 32; off > 0; off >>= 1) acc += __shfl_xor(acc, off);
    if (lane == 0) out[row] = acc + pb;
  }
}

// ---------------------------------------------------------------------------
extern "C" void kernel_launch(void* const* d_in, const int* in_sizes, int n_in,
                              void* d_out, int out_size, void* d_ws, size_t ws_size,
                              hipStream_t stream) {
  const int*   question = (const int*)d_in[0];
  const int*   response = (const int*)d_in[1];
  const float* mask     = (const float*)d_in[2];
  const float* k_emb    = (const float*)d_in[3];
  const float* v_emb    = (const float*)d_in[4];
  const float* Mk       = (const float*)d_in[5];
  const float* Mv0      = (const float*)d_in[6];
  const float* e_W      = (const float*)d_in[7];
  const float* e_b      = (const float*)d_in[8];
  const float* a_W      = (const float*)d_in[9];
  const float* a_b      = (const float*)d_in[10];
  const float* f_W      = (const float*)d_in[11];
  const float* f_b      = (const float*)d_in[12];
  const float* p_W      = (const float*)d_in[13];
  const float* p_b      = (const float*)d_in[14];
  float* out = (float*)d_out;

  // workspace layout (floats)
  const size_t wN  = (size_t)BB * TT * WPAD;       // 1,703,936
  const size_t eN  = (size_t)BB * TT * 64;         // 2,097,152
  const size_t r2N = 2ull * BB * (TT - 1) * 64;    // 4,186,112
  float* ws = (float*)d_ws;
  float* w_buf  = ws;
  float* e_buf  = w_buf + wN;
  float* a_buf  = e_buf + eN;
  float* read2  = a_buf + eN;
  float* AB_arr = read2 + r2N;
  const size_t baseN = wN + 2 * eN + r2N;          // 10,084,352 floats

  // choose the largest chunk count C that fits the workspace
  int C = 32, logC = 5;
  while (C >= 2) {
    const size_t need = (baseN + 9600ull * BB * C) * sizeof(float);
    if (need <= ws_size) break;
    C >>= 1; logC -= 1;
  }
  int useChunks = (C >= 2);
  if (!useChunks) { C = 1; logC = 0; }
  const int L = TT / C;
  float* entry = AB_arr + 6400ull * BB * C;

  hipLaunchKernelGGL(kPre, dim3(2048), dim3(256), 0, stream,
                     question, response, mask, k_emb, v_emb, Mk,
                     e_W, e_b, a_W, a_b, w_buf, e_buf, a_buf);

  if (C == 32) {
    hipLaunchKernelGGL(kA16, dim3(1024), dim3(256), 0, stream,
                       w_buf, e_buf, a_buf, AB_arr);
    hipLaunchKernelGGL(kB_entry, dim3((BB * MM * 64 + 255) / 256), dim3(256),
                       0, stream, AB_arr, Mv0, entry, C);
    hipLaunchKernelGGL(kC16, dim3(1024), dim3(256), 0, stream,
                       w_buf, e_buf, a_buf, entry, read2);
  } else {
    if (useChunks) {
      const int ublocksA = (BB * C * 2 + 3) / 4;
      hipLaunchKernelGGL(kA_chunk, dim3(ublocksA), dim3(256), 0, stream,
                         w_buf, e_buf, a_buf, AB_arr, logC, L);
      hipLaunchKernelGGL(kB_entry, dim3((BB * MM * 64 + 255) / 256), dim3(256),
                         0, stream, AB_arr, Mv0, entry, C);
    }
    const int ublocksC = (BB * C * 2 + 3) / 4;
    hipLaunchKernelGGL(kC_read, dim3(ublocksC), dim3(256), 0, stream,
                       w_buf, e_buf, a_buf, entry, Mv0, read2,
                       logC, L, useChunks ? 0 : 1);
  }

  hipLaunchKernelGGL(k3_out, dim3(1024), dim3(256), 0, stream,
                     question, k_emb, read2, f_W, f_b, p_W, p_b, out);
}

// Round 9
// 225.601 us; speedup vs baseline: 1.0805x; 1.0383x over previous
//
#include <hip/hip_runtime.h>
#include <cstddef>

// Problem constants (from reference)
#define QN 10000
#define DD 64
#define MM 50
#define BB 64
#define TT 512
#define WPAD 52   // padded w row stride in floats (208 B -> 16B-aligned rows)
#define MG 25     // m's per wave in the 2-way m-split scan kernels

// Pin a float array in VGPRs: defeats the rematerialize-from-memory heuristic
// without occupancy hints (hints proven harmful in R7/R8).
#define PIN(arr, n)                                        \
  _Pragma("unroll") for (int _p = 0; _p < (n); ++_p)       \
      asm volatile("" : "+v"((arr)[_p]));

// ===========================================================================
// kPre: per-timestep precompute, 3 roles (w / e / a), 4 rows per iteration.
// KEY CHANGE vs R6: embedding rows are fetched with PER-LANE vector loads
// (coalesced, in-order vmcnt, 4 in flight) and re-broadcast through LDS
// float4 reads, instead of wave-uniform s_loads. SMEM returns out-of-order
// so uniform loads force full lgkmcnt(0) drains every few loads (SGPR-bound)
// -- that serialization was kPre's 43-63us (R8 counters: VALU 22%, HBM 10%,
// occ 19% = no pipe busy).
// ===========================================================================
__global__ __launch_bounds__(256) void kPre(
    const int* __restrict__ question, const int* __restrict__ response,
    const float* __restrict__ mask,
    const float* __restrict__ k_emb, const float* __restrict__ v_emb,
    const float* __restrict__ Mk,
    const float* __restrict__ e_W, const float* __restrict__ e_b,
    const float* __restrict__ a_W, const float* __restrict__ a_b,
    float* __restrict__ w_buf, float* __restrict__ e_buf,
    float* __restrict__ a_buf) {
  __shared__ float stg[4][4][64];                      // [wave][rowslot][i]
  const int lane = (int)(threadIdx.x & 63);
  const int ws = __builtin_amdgcn_readfirstlane((int)(threadIdx.x >> 6));
  const int gw = blockIdx.x * 4 + ws;
  const int NW = gridDim.x * 4;
  const int third = NW / 3;
  if (gw >= 3 * third) return;
  const int role = gw / third;
  const int idx = gw - role * third;
  const int stride4 = third * 4;

  if (role == 0) {                        // ---- role: w (softmax), 4 rows/iter
    float mk[64];
    const int mrow = lane < MM ? lane : (MM - 1);
#pragma unroll
    for (int i = 0; i < 64; i += 4) {
      const float4 t4 = *(const float4*)(Mk + mrow * 64 + i);
      mk[i] = t4.x; mk[i + 1] = t4.y; mk[i + 2] = t4.z; mk[i + 3] = t4.w;
    }
    PIN(mk, 64)
    for (int base = idx * 4; base < BB * TT; base += stride4) {
      const int4 q4 = *(const int4*)(question + base);   // 1 scalar load
      // 4 independent per-lane gathers (coalesced 256B each, all in flight)
      const float kl0 = k_emb[(size_t)q4.x * 64 + lane];
      const float kl1 = k_emb[(size_t)q4.y * 64 + lane];
      const float kl2 = k_emb[(size_t)q4.z * 64 + lane];
      const float kl3 = k_emb[(size_t)q4.w * 64 + lane];
      stg[ws][0][lane] = kl0;
      stg[ws][1][lane] = kl1;
      stg[ws][2][lane] = kl2;
      stg[ws][3][lane] = kl3;             // wave-private: no barrier needed
      float lm[4];
#pragma unroll
      for (int r = 0; r < 4; ++r) {
        float l0 = 0.f, l1 = 0.f, l2 = 0.f, l3 = 0.f;
#pragma unroll
        for (int i = 0; i < 64; i += 4) {
          const float4 kv = *(const float4*)&stg[ws][r][i]; // LDS broadcast
          l0 = fmaf(kv.x, mk[i], l0);
          l1 = fmaf(kv.y, mk[i + 1], l1);
          l2 = fmaf(kv.z, mk[i + 2], l2);
          l3 = fmaf(kv.w, mk[i + 3], l3);
        }
        lm[r] = (l0 + l1) + (l2 + l3);
      }
#pragma unroll
      for (int r = 0; r < 4; ++r) {
        float lv = (lane < MM) ? lm[r] : -3.4e38f;
#pragma unroll
        for (int off = 32; off > 0; off >>= 1) lv = fmaxf(lv, __shfl_xor(lv, off));
        float pe = (lane < MM) ? __expf(lm[r] - lv) : 0.f;
        float ss = pe;
#pragma unroll
        for (int off = 32; off > 0; off >>= 1) ss += __shfl_xor(ss, off);
        if (lane < MM) w_buf[(size_t)(base + r) * WPAD + lane] = pe / ss;
      }
    }
  } else if (role == 1) {                 // ---- role: e, 4 rows/iter
    float ew[64];
#pragma unroll
    for (int i = 0; i < 64; ++i) ew[i] = e_W[i * 64 + lane];
    PIN(ew, 64)
    const float eb = e_b[lane];
    for (int base = idx * 4; base < BB * TT; base += stride4) {
      const int4 q4 = *(const int4*)(question + base);
      const int4 r4 = *(const int4*)(response + base);
      const float4 m4 = *(const float4*)(mask + base);
      const float vl0 = v_emb[((size_t)q4.x + (size_t)QN * r4.x) * 64 + lane];
      const float vl1 = v_emb[((size_t)q4.y + (size_t)QN * r4.y) * 64 + lane];
      const float vl2 = v_emb[((size_t)q4.z + (size_t)QN * r4.z) * 64 + lane];
      const float vl3 = v_emb[((size_t)q4.w + (size_t)QN * r4.w) * 64 + lane];
      stg[ws][0][lane] = vl0;
      stg[ws][1][lane] = vl1;
      stg[ws][2][lane] = vl2;
      stg[ws][3][lane] = vl3;
      float e00 = eb, e01 = 0.f, e10 = eb, e11 = 0.f;
      float e20 = eb, e21 = 0.f, e30 = eb, e31 = 0.f;
#pragma unroll
      for (int i = 0; i < 64; i += 4) {
        const float4 v0 = *(const float4*)&stg[ws][0][i];
        const float4 v1 = *(const float4*)&stg[ws][1][i];
        const float4 v2 = *(const float4*)&stg[ws][2][i];
        const float4 v3 = *(const float4*)&stg[ws][3][i];
        e00 = fmaf(v0.x, ew[i], e00);     e01 = fmaf(v0.y, ew[i + 1], e01);
        e00 = fmaf(v0.z, ew[i + 2], e00); e01 = fmaf(v0.w, ew[i + 3], e01);
        e10 = fmaf(v1.x, ew[i], e10);     e11 = fmaf(v1.y, ew[i + 1], e11);
        e10 = fmaf(v1.z, ew[i + 2], e10); e11 = fmaf(v1.w, ew[i + 3], e11);
        e20 = fmaf(v2.x, ew[i], e20);     e21 = fmaf(v2.y, ew[i + 1], e21);
        e20 = fmaf(v2.z, ew[i + 2], e20); e21 = fmaf(v2.w, ew[i + 3], e21);
        e30 = fmaf(v3.x, ew[i], e30);     e31 = fmaf(v3.y, ew[i + 1], e31);
        e30 = fmaf(v3.z, ew[i + 2], e30); e31 = fmaf(v3.w, ew[i + 3], e31);
      }
      const float mf0 = (m4.x == 1.0f) ? 1.0f : 0.0f;
      const float mf1 = (m4.y == 1.0f) ? 1.0f : 0.0f;
      const float mf2 = (m4.z == 1.0f) ? 1.0f : 0.0f;
      const float mf3 = (m4.w == 1.0f) ? 1.0f : 0.0f;
      e_buf[(size_t)(base + 0) * 64 + lane] = mf0 / (1.f + __expf(-(e00 + e01)));
      e_buf[(size_t)(base + 1) * 64 + lane] = mf1 / (1.f + __expf(-(e10 + e11)));
      e_buf[(size_t)(base + 2) * 64 + lane] = mf2 / (1.f + __expf(-(e20 + e21)));
      e_buf[(size_t)(base + 3) * 64 + lane] = mf3 / (1.f + __expf(-(e30 + e31)));
    }
  } else {                                // ---- role: a, 4 rows/iter
    float aw[64];
#pragma unroll
    for (int i = 0; i < 64; ++i) aw[i] = a_W[i * 64 + lane];
    PIN(aw, 64)
    const float ab = a_b[lane];
    for (int base = idx * 4; base < BB * TT; base += stride4) {
      const int4 q4 = *(const int4*)(question + base);
      const int4 r4 = *(const int4*)(response + base);
      const float4 m4 = *(const float4*)(mask + base);
      const float vl0 = v_emb[((size_t)q4.x + (size_t)QN * r4.x) * 64 + lane];
      const float vl1 = v_emb[((size_t)q4.y + (size_t)QN * r4.y) * 64 + lane];
      const float vl2 = v_emb[((size_t)q4.z + (size_t)QN * r4.z) * 64 + lane];
      const float vl3 = v_emb[((size_t)q4.w + (size_t)QN * r4.w) * 64 + lane];
      stg[ws][0][lane] = vl0;
      stg[ws][1][lane] = vl1;
      stg[ws][2][lane] = vl2;
      stg[ws][3][lane] = vl3;
      float a00 = ab, a01 = 0.f, a10 = ab, a11 = 0.f;
      float a20 = ab, a21 = 0.f, a30 = ab, a31 = 0.f;
#pragma unroll
      for (int i = 0; i < 64; i += 4) {
        const float4 v0 = *(const float4*)&stg[ws][0][i];
        const float4 v1 = *(const float4*)&stg[ws][1][i];
        const float4 v2 = *(const float4*)&stg[ws][2][i];
        const float4 v3 = *(const float4*)&stg[ws][3][i];
        a00 = fmaf(v0.x, aw[i], a00);     a01 = fmaf(v0.y, aw[i + 1], a01);
        a00 = fmaf(v0.z, aw[i + 2], a00); a01 = fmaf(v0.w, aw[i + 3], a01);
        a10 = fmaf(v1.x, aw[i], a10);     a11 = fmaf(v1.y, aw[i + 1], a11);
        a10 = fmaf(v1.z, aw[i + 2], a10); a11 = fmaf(v1.w, aw[i + 3], a11);
        a20 = fmaf(v2.x, aw[i], a20);     a21 = fmaf(v2.y, aw[i + 1], a21);
        a20 = fmaf(v2.z, aw[i + 2], a20); a21 = fmaf(v2.w, aw[i + 3], a21);
        a30 = fmaf(v3.x, aw[i], a30);     a31 = fmaf(v3.y, aw[i + 1], a31);
        a30 = fmaf(v3.z, aw[i + 2], a30); a31 = fmaf(v3.w, aw[i + 3], a31);
      }
      const float mf0 = (m4.x == 1.0f) ? 1.0f : 0.0f;
      const float mf1 = (m4.y == 1.0f) ? 1.0f : 0.0f;
      const float mf2 = (m4.z == 1.0f) ? 1.0f : 0.0f;
      const float mf3 = (m4.w == 1.0f) ? 1.0f : 0.0f;
      const float s0 = a00 + a01, s1 = a10 + a11, s2 = a20 + a21, s3 = a30 + a31;
      a_buf[(size_t)(base + 0) * 64 + lane] = mf0 * (1.f - 2.f / (__expf(2.f * s0) + 1.f));
      a_buf[(size_t)(base + 1) * 64 + lane] = mf1 * (1.f - 2.f / (__expf(2.f * s1) + 1.f));
      a_buf[(size_t)(base + 2) * 64 + lane] = mf2 * (1.f - 2.f / (__expf(2.f * s2) + 1.f));
      a_buf[(size_t)(base + 3) * 64 + lane] = mf3 * (1.f - 2.f / (__expf(2.f * s3) + 1.f));
    }
  }
}

// ===========================================================================
// kA16: C=32 specialized compose (L=16, fully unrolled), prefetch-all ev/av.
// (unchanged from R6)
// ===========================================================================
__global__ __launch_bounds__(256) void kA16(
    const float* __restrict__ w_buf, const float* __restrict__ e_buf,
    const float* __restrict__ a_buf, float* __restrict__ AB) {
  const int lane = (int)(threadIdx.x & 63);
  const int wslot = __builtin_amdgcn_readfirstlane((int)(threadIdx.x >> 6));
  const int u2 = blockIdx.x * 4 + wslot;
  if (u2 >= BB * 32 * 2) return;
  const int g = u2 & 1;
  const int unit = u2 >> 1;                            // b*32 + c
  const int b = unit >> 5;
  const int c = unit & 31;
  const size_t rowbase = (size_t)b * TT + c * 16;
  const size_t eb0 = rowbase * 64 + lane;

  float ev[16], av[16];
#pragma unroll
  for (int j = 0; j < 16; ++j) {
    ev[j] = e_buf[eb0 + (size_t)j * 64];
    av[j] = a_buf[eb0 + (size_t)j * 64];
  }

  float Am[MG], Bm[MG];
#pragma unroll
  for (int m = 0; m < MG; ++m) { Am[m] = 1.f; Bm[m] = 0.f; }

#pragma unroll
  for (int j = 0; j < 16; ++j) {
    const float* __restrict__ wr = w_buf + (rowbase + j) * WPAD + g * MG;
#pragma unroll
    for (int m = 0; m < MG; ++m) {
      const float wm = wr[m];
      const float al = fmaf(-wm, ev[j], 1.0f);
      const float be = wm * av[j];
      Am[m] *= al;
      Bm[m] = fmaf(Bm[m], al, be);
    }
  }
  float* __restrict__ abp = AB + (size_t)unit * 6400 + (g * MG) * 128 + lane * 2;
#pragma unroll
  for (int m = 0; m < MG; ++m) {
    float2 o; o.x = Am[m]; o.y = Bm[m];
    *(float2*)(abp + m * 128) = o;
  }
}

// ===========================================================================
// kB: sequential over C chunks, parallel over B*M*D. (unchanged from R6)
// ===========================================================================
__global__ __launch_bounds__(256) void kB_entry(
    const float* __restrict__ AB, const float* __restrict__ Mv0,
    float* __restrict__ entry, int C) {
  const int NT = gridDim.x * 256;
  for (int idx = blockIdx.x * 256 + (int)threadIdx.x; idx < BB * MM * 64;
       idx += NT) {
    const int b = idx / (MM * 64);
    const int r = idx - b * (MM * 64);                 // m*64 + d
    float s = Mv0[r];
    const float* __restrict__ abp = AB + (size_t)b * C * 6400 + (size_t)r * 2;
    float* __restrict__ ep = entry + (size_t)b * C * 3200 + r;
    if (C == 32) {
      float2 ab[32];
#pragma unroll
      for (int c = 0; c < 32; ++c)
        ab[c] = *(const float2*)(abp + (size_t)c * 6400);
#pragma unroll
      for (int c = 0; c < 32; ++c) {
        ep[(size_t)c * 3200] = s;
        s = fmaf(ab[c].x, s, ab[c].y);
      }
    } else {
      float2 cur = *(const float2*)(abp);
      for (int c = 0; c < C; ++c) {
        ep[(size_t)c * 3200] = s;
        float2 nxt; nxt.x = 1.f; nxt.y = 0.f;
        if (c + 1 < C) nxt = *(const float2*)(abp + (size_t)(c + 1) * 6400);
        s = fmaf(cur.x, s, cur.y);
        cur = nxt;
      }
    }
  }
}

// ===========================================================================
// kC16: C=32 specialized replay (unchanged from R6)
// ===========================================================================
__global__ __launch_bounds__(256) void kC16(
    const float* __restrict__ w_buf, const float* __restrict__ e_buf,
    const float* __restrict__ a_buf, const float* __restrict__ entry,
    float* __restrict__ read2) {
  const int lane = (int)(threadIdx.x & 63);
  const int wslot = __builtin_amdgcn_readfirstlane((int)(threadIdx.x >> 6));
  const int u2 = blockIdx.x * 4 + wslot;
  if (u2 >= BB * 32 * 2) return;
  const int g = u2 & 1;
  const int unit = u2 >> 1;                            // b*32 + c
  const int b = unit >> 5;
  const int c = unit & 31;
  const size_t RN = (size_t)BB * (TT - 1) * 64;
  const size_t rowbase = (size_t)b * TT + c * 16;
  const size_t eb0 = rowbase * 64 + lane;

  float ev[16], av[16];
#pragma unroll
  for (int j = 0; j < 16; ++j) {
    ev[j] = e_buf[eb0 + (size_t)j * 64];
    av[j] = a_buf[eb0 + (size_t)j * 64];
  }

  float s[MG];
  {
    const float* __restrict__ ep =
        entry + (size_t)unit * 3200 + (g * MG) * 64 + lane;
#pragma unroll
    for (int m = 0; m < MG; ++m) s[m] = ep[m * 64];    // 25 independent loads
  }

  const int t0 = c * 16;
  float* __restrict__ rb = read2 + (size_t)g * RN;
#pragma unroll
  for (int j = 0; j < 16; ++j) {
    const int t = t0 + j;
    const float* __restrict__ wr = w_buf + (rowbase + j) * WPAD + g * MG;
    if (t >= 1) {                                      // false only c==0,j==0
      float a0 = 0.f, a1 = 0.f;
#pragma unroll
      for (int m = 0; m < MG - 1; m += 2) {
        a0 = fmaf(wr[m], s[m], a0);
        a1 = fmaf(wr[m + 1], s[m + 1], a1);
      }
      a0 = fmaf(wr[MG - 1], s[MG - 1], a0);            // MG=25 is odd
      rb[((size_t)b * (TT - 1) + (t - 1)) * 64 + lane] = a0 + a1;
    }
#pragma unroll
    for (int m = 0; m < MG; ++m)
      s[m] = fmaf(wr[m], fmaf(-s[m], ev[j], av[j]), s[m]);
  }
}

// ===========================================================================
// Generic fallback scan kernels (used only if C != 32). (unchanged from R6)
// ===========================================================================
__global__ __launch_bounds__(256) void kA_chunk(
    const float* __restrict__ w_buf, const float* __restrict__ e_buf,
    const float* __restrict__ a_buf, float* __restrict__ AB, int logC, int L) {
  const int lane = (int)(threadIdx.x & 63);
  const int wslot = __builtin_amdgcn_readfirstlane((int)(threadIdx.x >> 6));
  const int NW = gridDim.x * 4;
  const int C = 1 << logC;
  for (int u2 = blockIdx.x * 4 + wslot; u2 < BB * C * 2; u2 += NW) {
    const int g = u2 & 1;
    const int unit = u2 >> 1;
    const int b = unit >> logC;
    const int c = unit & (C - 1);
    float Am[MG], Bm[MG];
#pragma unroll
    for (int m = 0; m < MG; ++m) { Am[m] = 1.f; Bm[m] = 0.f; }
    const size_t rowbase = (size_t)b * TT + c * L;
#pragma unroll 2
    for (int j = 0; j < L; ++j) {
      const size_t row = rowbase + j;
      const float ed = e_buf[row * 64 + lane];
      const float ad = a_buf[row * 64 + lane];
      const float* __restrict__ wr = w_buf + row * WPAD + g * MG;
#pragma unroll
      for (int m = 0; m < MG; ++m) {
        const float wm = wr[m];
        const float al = fmaf(-wm, ed, 1.0f);
        const float be = wm * ad;
        Am[m] *= al;
        Bm[m] = fmaf(Bm[m], al, be);
      }
    }
    float* __restrict__ abp = AB + (size_t)unit * 6400 + (g * MG) * 128 + lane * 2;
#pragma unroll
    for (int m = 0; m < MG; ++m) {
      float2 o; o.x = Am[m]; o.y = Bm[m];
      *(float2*)(abp + m * 128) = o;
    }
  }
}

__global__ __launch_bounds__(256) void kC_read(
    const float* __restrict__ w_buf, const float* __restrict__ e_buf,
    const float* __restrict__ a_buf, const float* __restrict__ entry,
    const float* __restrict__ Mv0, float* __restrict__ read2,
    int logC, int L, int use_mv0) {
  const int lane = (int)(threadIdx.x & 63);
  const int wslot = __builtin_amdgcn_readfirstlane((int)(threadIdx.x >> 6));
  const int NW = gridDim.x * 4;
  const int C = 1 << logC;
  const size_t RN = (size_t)BB * (TT - 1) * 64;
  for (int u2 = blockIdx.x * 4 + wslot; u2 < BB * C * 2; u2 += NW) {
    const int g = u2 & 1;
    const int unit = u2 >> 1;
    const int b = unit >> logC;
    const int c = unit & (C - 1);
    float s[MG];
    if (use_mv0) {
#pragma unroll
      for (int m = 0; m < MG; ++m) s[m] = Mv0[(g * MG + m) * 64 + lane];
    } else {
      const float* __restrict__ ep =
          entry + (size_t)unit * 3200 + (g * MG) * 64 + lane;
#pragma unroll
      for (int m = 0; m < MG; ++m) s[m] = ep[m * 64];
    }
    const int t0 = c * L;
    float* __restrict__ rb = read2 + (size_t)g * RN;
    for (int j = 0; j < L; ++j) {
      const int t = t0 + j;
      const size_t row = (size_t)b * TT + t;
      const float ed = e_buf[row * 64 + lane];
      const float ad = a_buf[row * 64 + lane];
      const float* __restrict__ wr = w_buf + row * WPAD + g * MG;
      if (t >= 1) {
        float a0 = 0.f, a1 = 0.f;
#pragma unroll
        for (int m = 0; m < MG - 1; m += 2) {
          a0 = fmaf(wr[m], s[m], a0);
          a1 = fmaf(wr[m + 1], s[m + 1], a1);
        }
        a0 = fmaf(wr[MG - 1], s[MG - 1], a0);
        rb[((size_t)b * (TT - 1) + (t - 1)) * 64 + lane] = a0 + a1;
      }
#pragma unroll
      for (int m = 0; m < MG; ++m)
        s[m] = fmaf(wr[m], fmaf(-s[m], ed, ad), s[m]);
    }
  }
}

// ===========================================================================
// k3: f = tanh([read | k_{t+1}] @ f_W + f_b); p = f @ p_W + p_b.
// KEY CHANGE vs R6 (46.5us, VGPR=72, VALU 28%): the 48 uniform s_loads/row
// (r0, r1, krow) are replaced by 3 per-lane vector loads + LDS float4
// broadcasts, with a 1-deep cross-row prefetch so the next row's HBM/L2
// latency hides under the current row's DS+VALU work. fw[128] is PINned
// in VGPRs (asm keep-alive) -- no occupancy hints.
// ===========================================================================
__global__ __launch_bounds__(256) void k3_out(
    const int* __restrict__ question, const float* __restrict__ k_emb,
    const float* __restrict__ read2,
    const float* __restrict__ f_W, const float* __restrict__ f_b,
    const float* __restrict__ p_W, const float* __restrict__ p_b,
    float* __restrict__ out) {
  __shared__ float stg[4][2][64];                      // [wave][{x,k}][i]
  const int lane = (int)(threadIdx.x & 63);
  const int ws = __builtin_amdgcn_readfirstlane((int)(threadIdx.x >> 6));
  const int NW = gridDim.x * 4;
  const size_t RN = (size_t)BB * (TT - 1) * 64;
  const int R = BB * (TT - 1);

  float fw[128];
#pragma unroll
  for (int i = 0; i < 128; ++i) fw[i] = f_W[i * 64 + lane];
  PIN(fw, 128)
  const float fb = f_b[lane];
  const float pw = p_W[lane];
  const float pb = p_b[0];

  int row = blockIdx.x * 4 + ws;
  float rd = 0.f, kl = 0.f;
  if (row < R) {                                       // prologue loads
    rd = read2[(size_t)row * 64 + lane] + read2[RN + (size_t)row * 64 + lane];
    const int b = row / (TT - 1);
    const int tp = row - b * (TT - 1);
    const int qn = question[b * TT + tp + 1];
    kl = k_emb[(size_t)qn * 64 + lane];
  }
  while (row < R) {
    const int nrow = row + NW;
    float nrd = 0.f, nkl = 0.f;
    if (nrow < R) {                                    // issue next-row loads
      nrd = read2[(size_t)nrow * 64 + lane] +
            read2[RN + (size_t)nrow * 64 + lane];
      const int nb = nrow / (TT - 1);
      const int ntp = nrow - nb * (TT - 1);
      const int nqn = question[nb * TT + ntp + 1];
      nkl = k_emb[(size_t)nqn * 64 + lane];
    }
    // stage current row, broadcast back, MLP
    stg[ws][0][lane] = rd;
    stg[ws][1][lane] = kl;                             // wave-private slots
    float f0 = fb, f1 = 0.f, f2 = 0.f, f3 = 0.f;
#pragma unroll
    for (int i = 0; i < 64; i += 4) {
      const float4 xv = *(const float4*)&stg[ws][0][i]; // LDS broadcast
      f0 = fmaf(xv.x, fw[i], f0);
      f1 = fmaf(xv.y, fw[i + 1], f1);
      f2 = fmaf(xv.z, fw[i + 2], f2);
      f3 = fmaf(xv.w, fw[i + 3], f3);
    }
#pragma unroll
    for (int i = 0; i < 64; i += 4) {
      const float4 kv = *(const float4*)&stg[ws][1][i];
      f0 = fmaf(kv.x, fw[64 + i], f0);
      f1 = fmaf(kv.y, fw[64 + i + 1], f1);
      f2 = fmaf(kv.z, fw[64 + i + 2], f2);
      f3 = fmaf(kv.w, fw[64 + i + 3], f3);
    }
    const float f = (f0 + f1) + (f2 + f3);
    const float t2 = __expf(2.f * f);
    const float fv = 1.f - 2.f / (t2 + 1.f);           // tanh
    float acc = fv * pw;
#pragma unroll
    for (int off = 32; off > 0; off >>= 1) acc += __shfl_xor(acc, off);
    if (lane == 0) out[row] = acc + pb;

    rd = nrd; kl = nkl; row = nrow;
  }
}

// ---------------------------------------------------------------------------
extern "C" void kernel_launch(void* const* d_in, const int* in_sizes, int n_in,
                              void* d_out, int out_size, void* d_ws, size_t ws_size,
                              hipStream_t stream) {
  const int*   question = (const int*)d_in[0];
  const int*   response = (const int*)d_in[1];
  const float* mask     = (const float*)d_in[2];
  const float* k_emb    = (const float*)d_in[3];
  const float* v_emb    = (const float*)d_in[4];
  const float* Mk       = (const float*)d_in[5];
  const float* Mv0      = (const float*)d_in[6];
  const float* e_W      = (const float*)d_in[7];
  const float* e_b      = (const float*)d_in[8];
  const float* a_W      = (const float*)d_in[9];
  const float* a_b      = (const float*)d_in[10];
  const float* f_W      = (const float*)d_in[11];
  const float* f_b      = (const float*)d_in[12];
  const float* p_W      = (const float*)d_in[13];
  const float* p_b      = (const float*)d_in[14];
  float* out = (float*)d_out;

  // workspace layout (floats)
  const size_t wN  = (size_t)BB * TT * WPAD;       // 1,703,936
  const size_t eN  = (size_t)BB * TT * 64;         // 2,097,152
  const size_t r2N = 2ull * BB * (TT - 1) * 64;    // 4,186,112
  float* ws = (float*)d_ws;
  float* w_buf  = ws;
  float* e_buf  = w_buf + wN;
  float* a_buf  = e_buf + eN;
  float* read2  = a_buf + eN;
  float* AB_arr = read2 + r2N;
  const size_t baseN = wN + 2 * eN + r2N;          // 10,084,352 floats

  // choose the largest chunk count C that fits the workspace
  int C = 32, logC = 5;
  while (C >= 2) {
    const size_t need = (baseN + 9600ull * BB * C) * sizeof(float);
    if (need <= ws_size) break;
    C >>= 1; logC -= 1;
  }
  int useChunks = (C >= 2);
  if (!useChunks) { C = 1; logC = 0; }
  const int L = TT / C;
  float* entry = AB_arr + 6400ull * BB * C;

  hipLaunchKernelGGL(kPre, dim3(2048), dim3(256), 0, stream,
                     question, response, mask, k_emb, v_emb, Mk,
                     e_W, e_b, a_W, a_b, w_buf, e_buf, a_buf);

  if (C == 32) {
    hipLaunchKernelGGL(kA16, dim3(1024), dim3(256), 0, stream,
                       w_buf, e_buf, a_buf, AB_arr);
    hipLaunchKernelGGL(kB_entry, dim3((BB * MM * 64 + 255) / 256), dim3(256),
                       0, stream, AB_arr, Mv0, entry, C);
    hipLaunchKernelGGL(kC16, dim3(1024), dim3(256), 0, stream,
                       w_buf, e_buf, a_buf, entry, read2);
  } else {
    if (useChunks) {
      const int ublocksA = (BB * C * 2 + 3) / 4;
      hipLaunchKernelGGL(kA_chunk, dim3(ublocksA), dim3(256), 0, stream,
                         w_buf, e_buf, a_buf, AB_arr, logC, L);
      hipLaunchKernelGGL(kB_entry, dim3((BB * MM * 64 + 255) / 256), dim3(256),
                         0, stream, AB_arr, Mv0, entry, C);
    }
    const int ublocksC = (BB * C * 2 + 3) / 4;
    hipLaunchKernelGGL(kC_read, dim3(ublocksC), dim3(256), 0, stream,
                       w_buf, e_buf, a_buf, entry, Mv0, read2,
                       logC, L, useChunks ? 0 : 1);
  }

  hipLaunchKernelGGL(k3_out, dim3(1024), dim3(256), 0, stream,
                     question, k_emb, read2, f_W, f_b, p_W, p_b, out);
}